// Round 20
// baseline (1553.877 us; speedup 1.0000x reference)
//
#include <hip/hip_runtime.h>
#include <hip/hip_bf16.h>
#include <math.h>

namespace {

constexpr int B  = 8;
constexpr int N  = 2048;     // power of two: n = p & 2047, b = p >> 11
constexpr int K  = 20;
constexpr int C1 = 64, C2 = 128, C3 = 256;
constexpr int NSLICE = 64;
constexpr double COUNT = 327680.0;   // B*N*K
constexpr double BNEPS = 1e-5;

// ---- workspace layout (bytes) ----
constexpr size_t OFF_IDX1  = 0;                                  // B*N*K int
constexpr size_t OFF_IDX2  = OFF_IDX1 + (size_t)B*N*K*4;         // B*N*K int
constexpr size_t OFF_X1D   = OFF_IDX2 + (size_t)B*N*K*4;         // B*N*C1 f64
constexpr size_t OFF_X2D   = OFF_X1D  + (size_t)B*N*C1*8;        // B*N*C2 f64
constexpr size_t OFF_STATS = OFF_X2D  + (size_t)B*N*C2*8;        // 2*NSLICE*C3 f64
constexpr size_t OFF_MI    = OFF_STATS+ (size_t)2*NSLICE*C3*8;   // 2*C3 f64
constexpr size_t OFF_X2F   = OFF_MI   + 4096;                    // B*N*C2 f32
constexpr size_t OFF_XX2F  = OFF_X2F  + (size_t)B*N*C2*4;        // B*N f32
constexpr size_t OFF_BIG   = OFF_XX2F + (size_t)B*N*4;           // shared big region
// big region, sequential lifetimes (within proven footprint):
//   {hmax1,hmin1 f64} -> {hmax2,hmin2 f64} -> dist f32 (134.2 MB) -> {hmax3,hmin3 f32}

typedef short  bf16x8 __attribute__((ext_vector_type(8)));
typedef float  f32x4  __attribute__((ext_vector_type(4)));

// ---- strict-rounding f32 helpers (block FMA contraction / reassociation) ----
__device__ __forceinline__ float fmul32(float a, float b){ return __fmul_rn(a,b); }
__device__ __forceinline__ float fadd32(float a, float b){ return __fadd_rn(a,b); }
__device__ __forceinline__ float fsub32(float a, float b){ return __fsub_rn(a,b); }

// ---- kNN on 3-D coords, numpy-f32-faithful values, wave-parallel top-20 ----
__global__ __launch_bounds__(256) void knn_xyz_wave(const float* __restrict__ x,
                                                    int* __restrict__ idxo) {
  int row  = blockIdx.x * 4 + (threadIdx.x >> 6);   // grid = B*N/4
  int lane = threadIdx.x & 63;
  int b = row >> 11, n = row & (N - 1);
  const float* xb = x + (size_t)b * N * 3;
  float xi0 = xb[(size_t)n*3], xi1 = xb[(size_t)n*3+1], xi2 = xb[(size_t)n*3+2];
  float xxi = fadd32(fadd32(fmul32(xi0,xi0), fmul32(xi1,xi1)), fmul32(xi2,xi2));
  float vals[32];
  #pragma unroll
  for (int t = 0; t < 32; ++t) {
    int j = lane + (t << 6);
    float a = xb[(size_t)j*3], c = xb[(size_t)j*3+1], d = xb[(size_t)j*3+2];
    float xxj   = fadd32(fadd32(fmul32(a,a), fmul32(c,c)), fmul32(d,d));
    float inner = fadd32(fadd32(fmul32(xi0,a), fmul32(xi1,c)), fmul32(xi2,d));
    vals[t] = fsub32(fsub32(fmul32(2.f, inner), xxi), xxj);
  }
  int* out = idxo + (size_t)row * K;
  for (int sel = 0; sel < K; ++sel) {
    float best = -INFINITY; int bt = 0;
    #pragma unroll
    for (int t = 0; t < 32; ++t)
      if (vals[t] > best) { best = vals[t]; bt = t; }
    int bcol = lane + (bt << 6);
    #pragma unroll
    for (int off = 32; off >= 1; off >>= 1) {
      float ov = __shfl_xor(best, off, 64);
      int   oc = __shfl_xor(bcol, off, 64);
      if (ov > best || (ov == best && oc < bcol)) { best = ov; bcol = oc; }
    }
    if (lane == 0) out[sel] = bcol;
    int kill = ((bcol & 63) == lane) ? (bcol >> 6) : 32;
    #pragma unroll
    for (int t = 0; t < 32; ++t) if (t == kill) vals[t] = -INFINITY;
  }
}

// ---- x2 -> f32 copy + numpy pairwise(n=128) sum of squares (BIT-FROZEN) ----
__global__ __launch_bounds__(64) void xx2f_kernel(const double* __restrict__ x2d,
                                                  float* __restrict__ x2f,
                                                  float* __restrict__ xx2f) {
  int row = blockIdx.x * 64 + threadIdx.x;   // grid = B*N/64
  const double* src = x2d + (size_t)row * C2;
  float* dst = x2f + (size_t)row * C2;
  float sq[C2];
  #pragma unroll 8
  for (int c = 0; c < C2; ++c) {
    float v = (float)src[c];
    dst[c] = v;
    sq[c] = fmul32(v, v);
  }
  float r0=sq[0], r1=sq[1], r2=sq[2], r3=sq[3], r4=sq[4], r5=sq[5], r6=sq[6], r7=sq[7];
  #pragma unroll
  for (int i = 8; i < 128; i += 8) {
    r0 = fadd32(r0, sq[i+0]); r1 = fadd32(r1, sq[i+1]);
    r2 = fadd32(r2, sq[i+2]); r3 = fadd32(r3, sq[i+3]);
    r4 = fadd32(r4, sq[i+4]); r5 = fadd32(r5, sq[i+5]);
    r6 = fadd32(r6, sq[i+6]); r7 = fadd32(r7, sq[i+7]);
  }
  xx2f[row] = fadd32(fadd32(fadd32(r0,r1), fadd32(r2,r3)),
                     fadd32(fadd32(r4,r5), fadd32(r6,r7)));
}

// ---- all-batch neg-distance matrix, f32 sequential (BIT-FROZEN inner) ----
__global__ __launch_bounds__(256) void dist_f32_kernel(const float* __restrict__ x2f,
                                                       const float* __restrict__ xx2f,
                                                       float* __restrict__ dist) {
  int bz = blockIdx.z;
  const float* x2b  = x2f  + (size_t)bz * N * C2;
  const float* xx2b = xx2f + (size_t)bz * N;
  float* db = dist + (size_t)bz * N * N;
  int ti = blockIdx.y * 64;
  int tj = blockIdx.x * 64;
  int tid = threadIdx.x;
  int tr = tid >> 4, tc = tid & 15;
  __shared__ float A[64][9], Bm[64][9];
  float acc[4][4];
  #pragma unroll
  for (int u = 0; u < 4; ++u)
    #pragma unroll
    for (int v = 0; v < 4; ++v) acc[u][v] = 0.f;
  for (int c0 = 0; c0 < C2; c0 += 8) {
    for (int i = tid; i < 512; i += 256) {
      int r = i >> 3, c = i & 7;
      A[r][c]  = x2b[(size_t)(ti + r)*C2 + c0 + c];
      Bm[r][c] = x2b[(size_t)(tj + r)*C2 + c0 + c];
    }
    __syncthreads();
    #pragma unroll
    for (int c = 0; c < 8; ++c) {       // ascending c: exact sequential order
      float a[4], bv[4];
      #pragma unroll
      for (int u = 0; u < 4; ++u) a[u] = A[tr*4 + u][c];
      #pragma unroll
      for (int v = 0; v < 4; ++v) bv[v] = Bm[tc*4 + v][c];
      #pragma unroll
      for (int u = 0; u < 4; ++u)
        #pragma unroll
        for (int v = 0; v < 4; ++v)
          acc[u][v] = fadd32(acc[u][v], fmul32(a[u], bv[v]));
    }
    __syncthreads();
  }
  #pragma unroll
  for (int u = 0; u < 4; ++u) {
    int i = ti + tr*4 + u;
    float xxi = xx2b[i];
    #pragma unroll
    for (int v = 0; v < 4; ++v) {
      int j = tj + tc*4 + v;
      db[(size_t)i*N + j] = fsub32(fsub32(fmul32(2.f, acc[u][v]), xxi), xx2b[j]);
    }
  }
}

// ---- wave-parallel top-20 on frozen dist values (coalesced reads) ----
__global__ __launch_bounds__(256) void knn_feat_wave(const float* __restrict__ dist,
                                                     int* __restrict__ idxo) {
  int row  = blockIdx.x * 4 + (threadIdx.x >> 6);   // grid = B*N/4
  int lane = threadIdx.x & 63;
  const float* dr = dist + (size_t)row * N;
  float vals[32];
  #pragma unroll
  for (int t = 0; t < 32; ++t) vals[t] = dr[lane + (t << 6)];   // coalesced
  int* out = idxo + (size_t)row * K;
  for (int sel = 0; sel < K; ++sel) {
    float best = -INFINITY; int bt = 0;
    #pragma unroll
    for (int t = 0; t < 32; ++t)
      if (vals[t] > best) { best = vals[t]; bt = t; }
    int bcol = lane + (bt << 6);
    #pragma unroll
    for (int off = 32; off >= 1; off >>= 1) {
      float ov = __shfl_xor(best, off, 64);
      int   oc = __shfl_xor(bcol, off, 64);
      if (ov > best || (ov == best && oc < bcol)) { best = ov; bcol = oc; }
    }
    if (lane == 0) out[sel] = bcol;
    int kill = ((bcol & 63) == lane) ? (bcol >> 6) : 32;
    #pragma unroll
    for (int t = 0; t < 32; ++t) if (t == kill) vals[t] = -INFINITY;
  }
}

// ---- layer 1 pass0: geometry + conv1 (BIT-FROZEN chain) + stats
// + f64 hmax/hmin store; writes R1/R2. ----
__global__ __launch_bounds__(64) void l1_p0(
    const float* __restrict__ x, const float* __restrict__ nrm,
    const float* __restrict__ w1, const int* __restrict__ idx1,
    double* __restrict__ sS, double* __restrict__ sQ,
    double* __restrict__ hmx1, double* __restrict__ hmn1,
    float* __restrict__ outR1, float* __restrict__ outR2) {
  int p = blockIdx.x;
  int tid = threadIdx.x;
  int b = p >> 11, n = p & (N - 1);
  __shared__ float  wl[C1 * 9];
  __shared__ double rotd[K][3];
  __shared__ double fld[K][9];
  for (int i = tid; i < C1 * 9; i += 64) wl[i] = w1[i];
  const float* xb = x + (size_t)b * N * 3;
  double nx = nrm[(size_t)p*3], ny = nrm[(size_t)p*3+1], nz = nrm[(size_t)p*3+2];
  double vx = ny, vy = -nx;
  double s = 1.0 / fmax(1.0 + nz, 1e-8);
  double vxy = vx * vy;
  double R1v[9];
  R1v[0] = 1.0 - s*(vy*vy); R1v[1] = s*vxy;           R1v[2] = vy;
  R1v[3] = s*vxy;           R1v[4] = 1.0 - s*(vx*vx); R1v[5] = -vx;
  R1v[6] = -vy;             R1v[7] = vx;              R1v[8] = 1.0 - s*(vx*vx + vy*vy);
  double xi0 = xb[(size_t)n*3], xi1 = xb[(size_t)n*3+1], xi2 = xb[(size_t)n*3+2];
  if (tid < K) {
    int j = idx1[(size_t)p*K + tid];
    double d0 = (double)xb[(size_t)j*3]   - xi0;
    double d1 = (double)xb[(size_t)j*3+1] - xi1;
    double d2 = (double)xb[(size_t)j*3+2] - xi2;
    rotd[tid][0] = R1v[0]*d0 + R1v[1]*d1 + R1v[2]*d2;
    rotd[tid][1] = R1v[3]*d0 + R1v[4]*d1 + R1v[5]*d2;
    rotd[tid][2] = R1v[6]*d0 + R1v[7]*d1 + R1v[8]*d2;
  }
  __syncthreads();
  double mx = 0.0, my = 0.0;
  #pragma unroll
  for (int k = 0; k < K; ++k) { mx += rotd[k][0]; my += rotd[k][1]; }
  mx /= 20.0; my /= 20.0;
  double r = sqrt(mx*mx + my*my);
  double ct = 1.0, st = 0.0;
  if (r > 0.0) { ct = mx / r; st = my / r; }   // cos/sin of atan2(my,mx)
  if (tid < K) {
    double r0 = rotd[tid][0], r1 = rotd[tid][1], r2 = rotd[tid][2];
    double a0 = ct*r0 + st*r1;
    double a1 = ct*r1 - st*r0;
    fld[tid][0] = a0;  fld[tid][1] = a1;   fld[tid][2] = r2;
    fld[tid][3] = a0;  fld[tid][4] = -a1;  fld[tid][5] = r2;   // xz-mirror
    fld[tid][6] = xi0; fld[tid][7] = xi1;  fld[tid][8] = xi2;  // x_rep
  }
  if (tid == 0) {
    float* o1 = outR1 + (size_t)p * 9;
    #pragma unroll
    for (int i = 0; i < 9; ++i) o1[i] = (float)R1v[i];
    float* o2 = outR2 + (size_t)p * 9;
    o2[0] = (float)ct;  o2[1] = (float)st; o2[2] = 0.f;
    o2[3] = (float)-st; o2[4] = (float)ct; o2[5] = 0.f;
    o2[6] = 0.f;        o2[7] = 0.f;       o2[8] = 1.f;
  }
  __syncthreads();
  int o = tid;
  double sum = 0., sq = 0., hmx = -INFINITY, hmn = INFINITY;
  #pragma unroll
  for (int k = 0; k < K; ++k) {
    double h = 0.;
    #pragma unroll
    for (int c = 0; c < 9; ++c) h = fma((double)wl[o*9 + c], fld[k][c], h);
    sum += h; sq += h*h;
    hmx = fmax(hmx, h); hmn = fmin(hmn, h);
  }
  hmx1[(size_t)p*C1 + o] = hmx;
  hmn1[(size_t)p*C1 + o] = hmn;
  int slice = p & (NSLICE - 1);
  atomicAdd(&sS[slice*C3 + o], sum);
  atomicAdd(&sQ[slice*C3 + o], sq);
}

// ---- layer 1 pass1 (light): BN+LReLU at h extremes ----
__global__ __launch_bounds__(256) void l1_p1_light(
    const double* __restrict__ hmx1, const double* __restrict__ hmn1,
    const double* __restrict__ mid, const float* __restrict__ g1,
    const float* __restrict__ b1,
    double* __restrict__ x1d, float* __restrict__ out448) {
  int i = blockIdx.x * 256 + threadIdx.x;   // grid = B*N*C1/256
  int p = i >> 6, o = i & 63;
  double m = mid[o], is = mid[C3 + o];
  double g = g1[o], bb = b1[o];
  double y1 = ((hmx1[i] - m) * is) * g + bb;
  y1 = y1 > 0.0 ? y1 : 0.2 * y1;
  double y2 = ((hmn1[i] - m) * is) * g + bb;
  y2 = y2 > 0.0 ? y2 : 0.2 * y2;
  double mxv = fmax(y1, y2);
  x1d[i] = mxv;
  out448[(size_t)p*448 + o] = (float)mxv;
}

// ---- conv2 core: r12-proven LDS op sequence, 128 threads (BIT-FROZEN) ----
__device__ __forceinline__ void conv2_core(const double* __restrict__ x1d,
                                           const int* __restrict__ idx,
                                           const float* __restrict__ w,
                                           int p, int tid, double (&acc)[K]) {
  int b = p >> 11;
  __shared__ double difL[K][C1];
  __shared__ double xiL[C1];
  __shared__ int jidx[K];
  if (tid < K) jidx[tid] = idx[(size_t)p*K + tid];
  if (tid < C1) xiL[tid] = x1d[(size_t)p*C1 + tid];
  __syncthreads();
  #pragma unroll 1
  for (int i = tid; i < K*C1; i += 128) {
    int k = i >> 6, c = i & 63;
    difL[k][c] = x1d[((size_t)b*N + jidx[k])*C1 + c] - xiL[c];
  }
  __syncthreads();
  const float* wr = w + (size_t)tid * (2*C1);
  #pragma unroll
  for (int k = 0; k < K; ++k) acc[k] = 0.0;
  // phase 1: diff operand, c ascending per acc
  #pragma unroll
  for (int c0 = 0; c0 < C1; c0 += 16) {
    double wd[16];
    #pragma unroll
    for (int i = 0; i < 16; ++i) wd[i] = (double)wr[c0+i];
    #pragma unroll
    for (int k = 0; k < K; ++k) {
      #pragma unroll
      for (int i = 0; i < 16; ++i) acc[k] = fma(wd[i], difL[k][c0+i], acc[k]);
    }
  }
  // phase 2: x_rep operand, c ascending per acc
  #pragma unroll
  for (int c0 = 0; c0 < C1; c0 += 16) {
    double wd[16], xiv[16];
    #pragma unroll
    for (int i = 0; i < 16; ++i) { wd[i] = (double)wr[C1+c0+i]; xiv[i] = xiL[c0+i]; }
    #pragma unroll
    for (int k = 0; k < K; ++k) {
      #pragma unroll
      for (int i = 0; i < 16; ++i) acc[k] = fma(wd[i], xiv[i], acc[k]);
    }
  }
}

// ---- conv2 pass0: conv ONCE + stats + hmax/hmin (f64) store (r15-proven) ----
__global__ __launch_bounds__(128, 1) void conv2_p0(
    const double* __restrict__ x1d, const int* __restrict__ idx,
    const float* __restrict__ w,
    double* __restrict__ sS, double* __restrict__ sQ,
    double* __restrict__ hmx2, double* __restrict__ hmn2) {
  int p = blockIdx.x;
  int tid = threadIdx.x;
  double acc[K];
  conv2_core(x1d, idx, w, p, tid, acc);
  double sum = 0., sq = 0., hmx = -INFINITY, hmn = INFINITY;
  #pragma unroll
  for (int k = 0; k < K; ++k) {
    sum += acc[k]; sq += acc[k]*acc[k];
    hmx = fmax(hmx, acc[k]); hmn = fmin(hmn, acc[k]);
  }
  hmx2[(size_t)p*C2 + tid] = hmx;
  hmn2[(size_t)p*C2 + tid] = hmn;
  int slice = p & (NSLICE - 1);
  atomicAdd(&sS[slice*C3 + tid], sum);
  atomicAdd(&sQ[slice*C3 + tid], sq);
}

// ---- conv2 pass1 (light): BN+LReLU at h extremes (monotone => exact) ----
__global__ __launch_bounds__(256) void conv2_p1_light(
    const double* __restrict__ hmx2, const double* __restrict__ hmn2,
    const double* __restrict__ mid, const float* __restrict__ gam,
    const float* __restrict__ bet,
    double* __restrict__ x2d, float* __restrict__ out448) {
  int i = blockIdx.x * 256 + threadIdx.x;   // grid = B*N*C2/256
  int p = i >> 7, o = i & 127;
  double m = mid[o], is = mid[C3 + o];
  double g = gam[o], bb = bet[o];
  double y1 = ((hmx2[i] - m) * is) * g + bb;
  y1 = y1 > 0.0 ? y1 : 0.2 * y1;
  double y2 = ((hmn2[i] - m) * is) * g + bb;
  y2 = y2 > 0.0 ? y2 : 0.2 * y2;
  double mxv = fmax(y1, y2);
  x2d[i] = mxv;
  out448[(size_t)p*448 + C1 + o] = (float)mxv;
}

// ---- conv3 pass0 MFMA (value path; bf16 inputs admissible):
// D[kn,o] = sum_c XJ[kn,c]*W[o,c] via mfma_f32_16x16x32_bf16, kn as M-dim.
// A lane l: row=l&15 (kn), k=(l>>4)*8+i. B lane l: col=l&15 (o), same k.
// D lane l, reg r: row=(l>>4)*4+r (kn), col=l&15 (o)  [m89-verified].
// M padded 20->32; garbage rows 20..31 masked in epilogue. ----
__global__ __launch_bounds__(256, 1) void conv3_p0_mfma(
    const float* __restrict__ x2f, const int* __restrict__ idx,
    const float* __restrict__ w,
    double* __restrict__ sS, double* __restrict__ sQ,
    float* __restrict__ hmx3, float* __restrict__ hmn3) {
  int p = blockIdx.x;
  int tid = threadIdx.x;
  int lane = tid & 63;
  int wv = tid >> 6;
  int b = p >> 11;
  __shared__ float4 xjB4[32 * 16];   // bf16 [kn][c], 16B slots, slot^(row&7) swizzle
  __shared__ float  xiL[C2];
  __shared__ float  baseL[C3];
  __shared__ int    jidx[K];
  if (tid < K) jidx[tid] = idx[(size_t)p*K + tid];
  if (tid < C2) xiL[tid] = x2f[(size_t)p*C2 + tid];
  __syncthreads();
  // stage xj rows 0..19 as bf16 with slot-XOR swizzle (rows 20..31 left as-is)
  #pragma unroll 1
  for (int i = tid; i < 320; i += 256) {
    int row = i >> 4, slot = i & 15;
    const float* src = x2f + ((size_t)b*N + jidx[row])*C2 + slot*8;
    bf16x8 pk;
    #pragma unroll
    for (int e = 0; e < 8; ++e) {
      __hip_bfloat16 hb = __float2bfloat16(src[e]);
      pk[e] = *reinterpret_cast<short*>(&hb);
    }
    *reinterpret_cast<bf16x8*>(&xjB4[row*16 + (slot ^ (row & 7))]) = pk;
  }
  // base[o] for all 256 o (folded xi part, f32 chain as r19)
  {
    const float* wr = w + (size_t)tid * (2*C2);
    float bs = 0.f;
    #pragma unroll
    for (int c0 = 0; c0 < C2; c0 += 32) {
      #pragma unroll
      for (int i = 0; i < 32; ++i)
        bs = fmaf(wr[C2+c0+i] - wr[c0+i], xiL[c0+i], bs);
    }
    baseL[tid] = bs;
  }
  __syncthreads();
  // A-frags (xj) once per wave: [mt][ks]
  bf16x8 afrag[2][4];
  #pragma unroll
  for (int mt = 0; mt < 2; ++mt) {
    #pragma unroll
    for (int ks = 0; ks < 4; ++ks) {
      int row = mt*16 + (lane & 15);
      int slot = ks*4 + (lane >> 4);
      afrag[mt][ks] = *reinterpret_cast<const bf16x8*>(&xjB4[row*16 + (slot ^ (row & 7))]);
    }
  }
  int slice = p & (NSLICE - 1);
  int g = lane >> 4;
  // N-tiles: 4 per wave
  #pragma unroll 1
  for (int nt = wv; nt < 16; nt += 4) {
    int oc = nt*16 + (lane & 15);
    // B-frags (w) packed on the fly from L2-hot w3
    f32x4 acc0 = {0.f, 0.f, 0.f, 0.f};
    f32x4 acc1 = {0.f, 0.f, 0.f, 0.f};
    #pragma unroll
    for (int ks = 0; ks < 4; ++ks) {
      const float* wsrc = w + (size_t)oc * (2*C2) + ks*32 + g*8;
      bf16x8 bw;
      #pragma unroll
      for (int e = 0; e < 8; ++e) {
        __hip_bfloat16 hb = __float2bfloat16(wsrc[e]);
        bw[e] = *reinterpret_cast<short*>(&hb);
      }
      acc0 = __builtin_amdgcn_mfma_f32_16x16x32_bf16(afrag[0][ks], bw, acc0, 0, 0, 0);
      acc1 = __builtin_amdgcn_mfma_f32_16x16x32_bf16(afrag[1][ks], bw, acc1, 0, 0, 0);
    }
    // epilogue: lane col = oc; acc0 rows kn = g*4+r (0..15, valid);
    // acc1 rows kn = 16+g*4+r (valid only g==0 -> kn 16..19)
    float bs = baseL[oc];
    float s = 0.f, q = 0.f, mxv = -INFINITY, mnv = INFINITY;
    #pragma unroll
    for (int r = 0; r < 4; ++r) {
      float h = bs + acc0[r];
      s += h; q += h*h;
      mxv = fmaxf(mxv, h); mnv = fminf(mnv, h);
    }
    if (g == 0) {
      #pragma unroll
      for (int r = 0; r < 4; ++r) {
        float h = bs + acc1[r];
        s += h; q += h*h;
        mxv = fmaxf(mxv, h); mnv = fminf(mnv, h);
      }
    }
    // combine the 4 lane-groups (same oc): xor 16, 32
    #pragma unroll
    for (int off = 16; off <= 32; off <<= 1) {
      s += __shfl_xor(s, off, 64);
      q += __shfl_xor(q, off, 64);
      mxv = fmaxf(mxv, __shfl_xor(mxv, off, 64));
      mnv = fminf(mnv, __shfl_xor(mnv, off, 64));
    }
    if (g == 0) {
      hmx3[(size_t)p*C3 + oc] = mxv;
      hmn3[(size_t)p*C3 + oc] = mnv;
      atomicAdd(&sS[slice*C3 + oc], (double)s);
      atomicAdd(&sQ[slice*C3 + oc], (double)q);
    }
  }
}

// ---- conv3 pass1 (light): BN+LReLU at extremes, fmax -> out ----
__global__ __launch_bounds__(256) void conv3_p1_light(
    const float* __restrict__ hmx3, const float* __restrict__ hmn3,
    const double* __restrict__ mid, const float* __restrict__ gam,
    const float* __restrict__ bet, float* __restrict__ out448) {
  int i = blockIdx.x * 256 + threadIdx.x;   // grid = B*N*C3/256
  int p = i >> 8, o = i & 255;
  float m = (float)mid[o], is = (float)mid[C3 + o];
  float g = gam[o], bb = bet[o];
  float y1 = (hmx3[i] - m) * is * g + bb;
  y1 = y1 > 0.f ? y1 : 0.2f * y1;
  float y2 = (hmn3[i] - m) * is * g + bb;
  y2 = y2 > 0.f ? y2 : 0.2f * y2;
  out448[(size_t)p*448 + C1 + C2 + o] = fmaxf(y1, y2);
}

// ---- finalize BN stats (f64) ----
__global__ void finalize_stats(const double* __restrict__ sS, const double* __restrict__ sQ,
                               double* __restrict__ mid, int C) {
  int o = threadIdx.x;
  if (o >= C) return;
  double s = 0., q = 0.;
  for (int i = 0; i < NSLICE; ++i) { s += sS[i*C3 + o]; q += sQ[i*C3 + o]; }
  double m = s / COUNT;
  double v = q / COUNT - m*m;
  mid[o] = m;
  mid[C3 + o] = 1.0 / sqrt(v + BNEPS);
}

} // namespace

extern "C" void kernel_launch(void* const* d_in, const int* in_sizes, int n_in,
                              void* d_out, int out_size, void* d_ws, size_t ws_size,
                              hipStream_t stream) {
  (void)in_sizes; (void)n_in; (void)out_size; (void)ws_size;
  const float* x   = (const float*)d_in[0];
  const float* nrm = (const float*)d_in[1];
  const float* w1  = (const float*)d_in[2];
  const float* g1  = (const float*)d_in[3];
  const float* b1  = (const float*)d_in[4];
  const float* w2  = (const float*)d_in[5];
  const float* g2  = (const float*)d_in[6];
  const float* b2  = (const float*)d_in[7];
  const float* w3  = (const float*)d_in[8];
  const float* g3  = (const float*)d_in[9];
  const float* b3  = (const float*)d_in[10];
  float* out = (float*)d_out;
  char*  ws  = (char*)d_ws;

  int*    idx1 = (int*)(ws + OFF_IDX1);
  int*    idx2 = (int*)(ws + OFF_IDX2);
  double* x1d  = (double*)(ws + OFF_X1D);
  double* x2d  = (double*)(ws + OFF_X2D);
  double* sS   = (double*)(ws + OFF_STATS);
  double* sQ   = sS + (size_t)NSLICE * C3;
  double* mid  = (double*)(ws + OFF_MI);
  float*  x2f  = (float*)(ws + OFF_X2F);
  float*  xx2f = (float*)(ws + OFF_XX2F);
  char*   big  = ws + OFF_BIG;
  double* hmx1 = (double*)big;                                   // l1_p0..p1
  double* hmn1 = hmx1 + (size_t)B*N*C1;
  double* hmx2 = (double*)big;                                   // conv2_p0..p1
  double* hmn2 = hmx2 + (size_t)B*N*C2;
  float*  dist = (float*)big;                                    // dist..knn_feat
  float*  hmx3 = (float*)big;                                    // conv3_p0..p1
  float*  hmn3 = hmx3 + (size_t)B*N*C3;

  float* outR1 = out + (size_t)B * N * 448;
  float* outR2 = outR1 + (size_t)B * N * 9;

  // kNN1 — numpy-f32-faithful values, wave-parallel selection
  knn_xyz_wave<<<B*N/4, 256, 0, stream>>>(x, idx1);

  // layer 1: geometry+conv once (bit-frozen chain) + extremes; light BN finish
  hipMemsetAsync(sS, 0, (size_t)2*NSLICE*C3*sizeof(double), stream);
  l1_p0<<<B*N, 64, 0, stream>>>(x, nrm, w1, idx1, sS, sQ, hmx1, hmn1, outR1, outR2);
  finalize_stats<<<1, C3, 0, stream>>>(sS, sQ, mid, C1);
  l1_p1_light<<<B*N*C1/256, 256, 0, stream>>>(hmx1, hmn1, mid, g1, b1, x1d, out);

  // layer 2: conv once (bit-frozen core) + extremes; light BN finish
  hipMemsetAsync(sS, 0, (size_t)2*NSLICE*C3*sizeof(double), stream);
  conv2_p0<<<B*N, 128, 0, stream>>>(x1d, idx1, w2, sS, sQ, hmx2, hmn2);
  finalize_stats<<<1, C3, 0, stream>>>(sS, sQ, mid, C2);
  conv2_p1_light<<<B*N*C2/256, 256, 0, stream>>>(hmx2, hmn2, mid, g2, b2, x2d, out);

  // kNN2 — numpy-f32-faithful, all batches fused; wave-parallel coalesced top-k
  xx2f_kernel<<<B*N/64, 64, 0, stream>>>(x2d, x2f, xx2f);
  dist_f32_kernel<<<dim3(N/64, N/64, B), 256, 0, stream>>>(x2f, xx2f, dist);
  knn_feat_wave<<<B*N/4, 256, 0, stream>>>(dist, idx2);

  // layer 3: MFMA conv once (bf16 value path) + extremes; light BN finish
  hipMemsetAsync(sS, 0, (size_t)2*NSLICE*C3*sizeof(double), stream);
  conv3_p0_mfma<<<B*N, 256, 0, stream>>>(x2f, idx2, w3, sS, sQ, hmx3, hmn3);
  finalize_stats<<<1, C3, 0, stream>>>(sS, sQ, mid, C3);
  conv3_p1_light<<<B*N*C3/256, 256, 0, stream>>>(hmx3, hmn3, mid, g3, b3, out);
}

// Round 21
// 841.695 us; speedup vs baseline: 1.8461x; 1.8461x over previous
//
#include <hip/hip_runtime.h>
#include <hip/hip_bf16.h>
#include <math.h>

namespace {

constexpr int B  = 8;
constexpr int N  = 2048;     // power of two: n = p & 2047, b = p >> 11
constexpr int K  = 20;
constexpr int C1 = 64, C2 = 128, C3 = 256;
constexpr int NSLICE = 64;
constexpr double COUNT = 327680.0;   // B*N*K
constexpr double BNEPS = 1e-5;

// ---- workspace layout (bytes) ----
constexpr size_t OFF_IDX1  = 0;                                  // B*N*K int
constexpr size_t OFF_IDX2  = OFF_IDX1 + (size_t)B*N*K*4;         // B*N*K int
constexpr size_t OFF_X1D   = OFF_IDX2 + (size_t)B*N*K*4;         // B*N*C1 f64
constexpr size_t OFF_X2D   = OFF_X1D  + (size_t)B*N*C1*8;        // B*N*C2 f64
constexpr size_t OFF_STATS = OFF_X2D  + (size_t)B*N*C2*8;        // 2*NSLICE*C3 f64
constexpr size_t OFF_MI    = OFF_STATS+ (size_t)2*NSLICE*C3*8;   // 2*C3 f64
constexpr size_t OFF_X2F   = OFF_MI   + 4096;                    // B*N*C2 f32
constexpr size_t OFF_XX2F  = OFF_X2F  + (size_t)B*N*C2*4;        // B*N f32
constexpr size_t OFF_WPK   = OFF_XX2F + (size_t)B*N*4;           // 16*4*64 bf16x8 = 64KB
constexpr size_t OFF_BIG   = OFF_WPK  + 65536;                   // shared big region
// big region, sequential lifetimes (within proven footprint):
//   {hmax1,hmin1 f64} -> {hmax2,hmin2 f64} -> dist f32 (134.2 MB)
//   -> {hmax3,hmin3 f32, baseB f32: 3 x 16.8 MB}

typedef short  bf16x8 __attribute__((ext_vector_type(8)));
typedef float  f32x4  __attribute__((ext_vector_type(4)));

// ---- strict-rounding f32 helpers (block FMA contraction / reassociation) ----
__device__ __forceinline__ float fmul32(float a, float b){ return __fmul_rn(a,b); }
__device__ __forceinline__ float fadd32(float a, float b){ return __fadd_rn(a,b); }
__device__ __forceinline__ float fsub32(float a, float b){ return __fsub_rn(a,b); }

// ---- kNN on 3-D coords, numpy-f32-faithful values, wave-parallel top-20 ----
__global__ __launch_bounds__(256) void knn_xyz_wave(const float* __restrict__ x,
                                                    int* __restrict__ idxo) {
  int row  = blockIdx.x * 4 + (threadIdx.x >> 6);   // grid = B*N/4
  int lane = threadIdx.x & 63;
  int b = row >> 11, n = row & (N - 1);
  const float* xb = x + (size_t)b * N * 3;
  float xi0 = xb[(size_t)n*3], xi1 = xb[(size_t)n*3+1], xi2 = xb[(size_t)n*3+2];
  float xxi = fadd32(fadd32(fmul32(xi0,xi0), fmul32(xi1,xi1)), fmul32(xi2,xi2));
  float vals[32];
  #pragma unroll
  for (int t = 0; t < 32; ++t) {
    int j = lane + (t << 6);
    float a = xb[(size_t)j*3], c = xb[(size_t)j*3+1], d = xb[(size_t)j*3+2];
    float xxj   = fadd32(fadd32(fmul32(a,a), fmul32(c,c)), fmul32(d,d));
    float inner = fadd32(fadd32(fmul32(xi0,a), fmul32(xi1,c)), fmul32(xi2,d));
    vals[t] = fsub32(fsub32(fmul32(2.f, inner), xxi), xxj);
  }
  int* out = idxo + (size_t)row * K;
  for (int sel = 0; sel < K; ++sel) {
    float best = -INFINITY; int bt = 0;
    #pragma unroll
    for (int t = 0; t < 32; ++t)
      if (vals[t] > best) { best = vals[t]; bt = t; }
    int bcol = lane + (bt << 6);
    #pragma unroll
    for (int off = 32; off >= 1; off >>= 1) {
      float ov = __shfl_xor(best, off, 64);
      int   oc = __shfl_xor(bcol, off, 64);
      if (ov > best || (ov == best && oc < bcol)) { best = ov; bcol = oc; }
    }
    if (lane == 0) out[sel] = bcol;
    int kill = ((bcol & 63) == lane) ? (bcol >> 6) : 32;
    #pragma unroll
    for (int t = 0; t < 32; ++t) if (t == kill) vals[t] = -INFINITY;
  }
}

// ---- x2 -> f32 copy + numpy pairwise(n=128) sum of squares (BIT-FROZEN) ----
__global__ __launch_bounds__(64) void xx2f_kernel(const double* __restrict__ x2d,
                                                  float* __restrict__ x2f,
                                                  float* __restrict__ xx2f) {
  int row = blockIdx.x * 64 + threadIdx.x;   // grid = B*N/64
  const double* src = x2d + (size_t)row * C2;
  float* dst = x2f + (size_t)row * C2;
  float sq[C2];
  #pragma unroll 8
  for (int c = 0; c < C2; ++c) {
    float v = (float)src[c];
    dst[c] = v;
    sq[c] = fmul32(v, v);
  }
  float r0=sq[0], r1=sq[1], r2=sq[2], r3=sq[3], r4=sq[4], r5=sq[5], r6=sq[6], r7=sq[7];
  #pragma unroll
  for (int i = 8; i < 128; i += 8) {
    r0 = fadd32(r0, sq[i+0]); r1 = fadd32(r1, sq[i+1]);
    r2 = fadd32(r2, sq[i+2]); r3 = fadd32(r3, sq[i+3]);
    r4 = fadd32(r4, sq[i+4]); r5 = fadd32(r5, sq[i+5]);
    r6 = fadd32(r6, sq[i+6]); r7 = fadd32(r7, sq[i+7]);
  }
  xx2f[row] = fadd32(fadd32(fadd32(r0,r1), fadd32(r2,r3)),
                     fadd32(fadd32(r4,r5), fadd32(r6,r7)));
}

// ---- all-batch neg-distance matrix, f32 sequential (BIT-FROZEN inner) ----
__global__ __launch_bounds__(256) void dist_f32_kernel(const float* __restrict__ x2f,
                                                       const float* __restrict__ xx2f,
                                                       float* __restrict__ dist) {
  int bz = blockIdx.z;
  const float* x2b  = x2f  + (size_t)bz * N * C2;
  const float* xx2b = xx2f + (size_t)bz * N;
  float* db = dist + (size_t)bz * N * N;
  int ti = blockIdx.y * 64;
  int tj = blockIdx.x * 64;
  int tid = threadIdx.x;
  int tr = tid >> 4, tc = tid & 15;
  __shared__ float A[64][9], Bm[64][9];
  float acc[4][4];
  #pragma unroll
  for (int u = 0; u < 4; ++u)
    #pragma unroll
    for (int v = 0; v < 4; ++v) acc[u][v] = 0.f;
  for (int c0 = 0; c0 < C2; c0 += 8) {
    for (int i = tid; i < 512; i += 256) {
      int r = i >> 3, c = i & 7;
      A[r][c]  = x2b[(size_t)(ti + r)*C2 + c0 + c];
      Bm[r][c] = x2b[(size_t)(tj + r)*C2 + c0 + c];
    }
    __syncthreads();
    #pragma unroll
    for (int c = 0; c < 8; ++c) {       // ascending c: exact sequential order
      float a[4], bv[4];
      #pragma unroll
      for (int u = 0; u < 4; ++u) a[u] = A[tr*4 + u][c];
      #pragma unroll
      for (int v = 0; v < 4; ++v) bv[v] = Bm[tc*4 + v][c];
      #pragma unroll
      for (int u = 0; u < 4; ++u)
        #pragma unroll
        for (int v = 0; v < 4; ++v)
          acc[u][v] = fadd32(acc[u][v], fmul32(a[u], bv[v]));
    }
    __syncthreads();
  }
  #pragma unroll
  for (int u = 0; u < 4; ++u) {
    int i = ti + tr*4 + u;
    float xxi = xx2b[i];
    #pragma unroll
    for (int v = 0; v < 4; ++v) {
      int j = tj + tc*4 + v;
      db[(size_t)i*N + j] = fsub32(fsub32(fmul32(2.f, acc[u][v]), xxi), xx2b[j]);
    }
  }
}

// ---- wave-parallel top-20 on frozen dist values (coalesced reads) ----
__global__ __launch_bounds__(256) void knn_feat_wave(const float* __restrict__ dist,
                                                     int* __restrict__ idxo) {
  int row  = blockIdx.x * 4 + (threadIdx.x >> 6);   // grid = B*N/4
  int lane = threadIdx.x & 63;
  const float* dr = dist + (size_t)row * N;
  float vals[32];
  #pragma unroll
  for (int t = 0; t < 32; ++t) vals[t] = dr[lane + (t << 6)];   // coalesced
  int* out = idxo + (size_t)row * K;
  for (int sel = 0; sel < K; ++sel) {
    float best = -INFINITY; int bt = 0;
    #pragma unroll
    for (int t = 0; t < 32; ++t)
      if (vals[t] > best) { best = vals[t]; bt = t; }
    int bcol = lane + (bt << 6);
    #pragma unroll
    for (int off = 32; off >= 1; off >>= 1) {
      float ov = __shfl_xor(best, off, 64);
      int   oc = __shfl_xor(bcol, off, 64);
      if (ov > best || (ov == best && oc < bcol)) { best = ov; bcol = oc; }
    }
    if (lane == 0) out[sel] = bcol;
    int kill = ((bcol & 63) == lane) ? (bcol >> 6) : 32;
    #pragma unroll
    for (int t = 0; t < 32; ++t) if (t == kill) vals[t] = -INFINITY;
  }
}

// ---- layer 1 pass0: geometry + conv1 (BIT-FROZEN chain) + stats
// + f64 hmax/hmin store; writes R1/R2. ----
__global__ __launch_bounds__(64) void l1_p0(
    const float* __restrict__ x, const float* __restrict__ nrm,
    const float* __restrict__ w1, const int* __restrict__ idx1,
    double* __restrict__ sS, double* __restrict__ sQ,
    double* __restrict__ hmx1, double* __restrict__ hmn1,
    float* __restrict__ outR1, float* __restrict__ outR2) {
  int p = blockIdx.x;
  int tid = threadIdx.x;
  int b = p >> 11, n = p & (N - 1);
  __shared__ float  wl[C1 * 9];
  __shared__ double rotd[K][3];
  __shared__ double fld[K][9];
  for (int i = tid; i < C1 * 9; i += 64) wl[i] = w1[i];
  const float* xb = x + (size_t)b * N * 3;
  double nx = nrm[(size_t)p*3], ny = nrm[(size_t)p*3+1], nz = nrm[(size_t)p*3+2];
  double vx = ny, vy = -nx;
  double s = 1.0 / fmax(1.0 + nz, 1e-8);
  double vxy = vx * vy;
  double R1v[9];
  R1v[0] = 1.0 - s*(vy*vy); R1v[1] = s*vxy;           R1v[2] = vy;
  R1v[3] = s*vxy;           R1v[4] = 1.0 - s*(vx*vx); R1v[5] = -vx;
  R1v[6] = -vy;             R1v[7] = vx;              R1v[8] = 1.0 - s*(vx*vx + vy*vy);
  double xi0 = xb[(size_t)n*3], xi1 = xb[(size_t)n*3+1], xi2 = xb[(size_t)n*3+2];
  if (tid < K) {
    int j = idx1[(size_t)p*K + tid];
    double d0 = (double)xb[(size_t)j*3]   - xi0;
    double d1 = (double)xb[(size_t)j*3+1] - xi1;
    double d2 = (double)xb[(size_t)j*3+2] - xi2;
    rotd[tid][0] = R1v[0]*d0 + R1v[1]*d1 + R1v[2]*d2;
    rotd[tid][1] = R1v[3]*d0 + R1v[4]*d1 + R1v[5]*d2;
    rotd[tid][2] = R1v[6]*d0 + R1v[7]*d1 + R1v[8]*d2;
  }
  __syncthreads();
  double mx = 0.0, my = 0.0;
  #pragma unroll
  for (int k = 0; k < K; ++k) { mx += rotd[k][0]; my += rotd[k][1]; }
  mx /= 20.0; my /= 20.0;
  double r = sqrt(mx*mx + my*my);
  double ct = 1.0, st = 0.0;
  if (r > 0.0) { ct = mx / r; st = my / r; }   // cos/sin of atan2(my,mx)
  if (tid < K) {
    double r0 = rotd[tid][0], r1 = rotd[tid][1], r2 = rotd[tid][2];
    double a0 = ct*r0 + st*r1;
    double a1 = ct*r1 - st*r0;
    fld[tid][0] = a0;  fld[tid][1] = a1;   fld[tid][2] = r2;
    fld[tid][3] = a0;  fld[tid][4] = -a1;  fld[tid][5] = r2;   // xz-mirror
    fld[tid][6] = xi0; fld[tid][7] = xi1;  fld[tid][8] = xi2;  // x_rep
  }
  if (tid == 0) {
    float* o1 = outR1 + (size_t)p * 9;
    #pragma unroll
    for (int i = 0; i < 9; ++i) o1[i] = (float)R1v[i];
    float* o2 = outR2 + (size_t)p * 9;
    o2[0] = (float)ct;  o2[1] = (float)st; o2[2] = 0.f;
    o2[3] = (float)-st; o2[4] = (float)ct; o2[5] = 0.f;
    o2[6] = 0.f;        o2[7] = 0.f;       o2[8] = 1.f;
  }
  __syncthreads();
  int o = tid;
  double sum = 0., sq = 0., hmx = -INFINITY, hmn = INFINITY;
  #pragma unroll
  for (int k = 0; k < K; ++k) {
    double h = 0.;
    #pragma unroll
    for (int c = 0; c < 9; ++c) h = fma((double)wl[o*9 + c], fld[k][c], h);
    sum += h; sq += h*h;
    hmx = fmax(hmx, h); hmn = fmin(hmn, h);
  }
  hmx1[(size_t)p*C1 + o] = hmx;
  hmn1[(size_t)p*C1 + o] = hmn;
  int slice = p & (NSLICE - 1);
  atomicAdd(&sS[slice*C3 + o], sum);
  atomicAdd(&sQ[slice*C3 + o], sq);
}

// ---- layer 1 pass1 (light): BN+LReLU at h extremes ----
__global__ __launch_bounds__(256) void l1_p1_light(
    const double* __restrict__ hmx1, const double* __restrict__ hmn1,
    const double* __restrict__ mid, const float* __restrict__ g1,
    const float* __restrict__ b1,
    double* __restrict__ x1d, float* __restrict__ out448) {
  int i = blockIdx.x * 256 + threadIdx.x;   // grid = B*N*C1/256
  int p = i >> 6, o = i & 63;
  double m = mid[o], is = mid[C3 + o];
  double g = g1[o], bb = b1[o];
  double y1 = ((hmx1[i] - m) * is) * g + bb;
  y1 = y1 > 0.0 ? y1 : 0.2 * y1;
  double y2 = ((hmn1[i] - m) * is) * g + bb;
  y2 = y2 > 0.0 ? y2 : 0.2 * y2;
  double mxv = fmax(y1, y2);
  x1d[i] = mxv;
  out448[(size_t)p*448 + o] = (float)mxv;
}

// ---- conv2 core: r12-proven LDS op sequence, 128 threads (BIT-FROZEN) ----
__device__ __forceinline__ void conv2_core(const double* __restrict__ x1d,
                                           const int* __restrict__ idx,
                                           const float* __restrict__ w,
                                           int p, int tid, double (&acc)[K]) {
  int b = p >> 11;
  __shared__ double difL[K][C1];
  __shared__ double xiL[C1];
  __shared__ int jidx[K];
  if (tid < K) jidx[tid] = idx[(size_t)p*K + tid];
  if (tid < C1) xiL[tid] = x1d[(size_t)p*C1 + tid];
  __syncthreads();
  #pragma unroll 1
  for (int i = tid; i < K*C1; i += 128) {
    int k = i >> 6, c = i & 63;
    difL[k][c] = x1d[((size_t)b*N + jidx[k])*C1 + c] - xiL[c];
  }
  __syncthreads();
  const float* wr = w + (size_t)tid * (2*C1);
  #pragma unroll
  for (int k = 0; k < K; ++k) acc[k] = 0.0;
  // phase 1: diff operand, c ascending per acc
  #pragma unroll
  for (int c0 = 0; c0 < C1; c0 += 16) {
    double wd[16];
    #pragma unroll
    for (int i = 0; i < 16; ++i) wd[i] = (double)wr[c0+i];
    #pragma unroll
    for (int k = 0; k < K; ++k) {
      #pragma unroll
      for (int i = 0; i < 16; ++i) acc[k] = fma(wd[i], difL[k][c0+i], acc[k]);
    }
  }
  // phase 2: x_rep operand, c ascending per acc
  #pragma unroll
  for (int c0 = 0; c0 < C1; c0 += 16) {
    double wd[16], xiv[16];
    #pragma unroll
    for (int i = 0; i < 16; ++i) { wd[i] = (double)wr[C1+c0+i]; xiv[i] = xiL[c0+i]; }
    #pragma unroll
    for (int k = 0; k < K; ++k) {
      #pragma unroll
      for (int i = 0; i < 16; ++i) acc[k] = fma(wd[i], xiv[i], acc[k]);
    }
  }
}

// ---- conv2 pass0: conv ONCE + stats + hmax/hmin (f64) store (r15-proven) ----
__global__ __launch_bounds__(128, 1) void conv2_p0(
    const double* __restrict__ x1d, const int* __restrict__ idx,
    const float* __restrict__ w,
    double* __restrict__ sS, double* __restrict__ sQ,
    double* __restrict__ hmx2, double* __restrict__ hmn2) {
  int p = blockIdx.x;
  int tid = threadIdx.x;
  double acc[K];
  conv2_core(x1d, idx, w, p, tid, acc);
  double sum = 0., sq = 0., hmx = -INFINITY, hmn = INFINITY;
  #pragma unroll
  for (int k = 0; k < K; ++k) {
    sum += acc[k]; sq += acc[k]*acc[k];
    hmx = fmax(hmx, acc[k]); hmn = fmin(hmn, acc[k]);
  }
  hmx2[(size_t)p*C2 + tid] = hmx;
  hmn2[(size_t)p*C2 + tid] = hmn;
  int slice = p & (NSLICE - 1);
  atomicAdd(&sS[slice*C3 + tid], sum);
  atomicAdd(&sQ[slice*C3 + tid], sq);
}

// ---- conv2 pass1 (light): BN+LReLU at h extremes (monotone => exact) ----
__global__ __launch_bounds__(256) void conv2_p1_light(
    const double* __restrict__ hmx2, const double* __restrict__ hmn2,
    const double* __restrict__ mid, const float* __restrict__ gam,
    const float* __restrict__ bet,
    double* __restrict__ x2d, float* __restrict__ out448) {
  int i = blockIdx.x * 256 + threadIdx.x;   // grid = B*N*C2/256
  int p = i >> 7, o = i & 127;
  double m = mid[o], is = mid[C3 + o];
  double g = gam[o], bb = bet[o];
  double y1 = ((hmx2[i] - m) * is) * g + bb;
  y1 = y1 > 0.0 ? y1 : 0.2 * y1;
  double y2 = ((hmn2[i] - m) * is) * g + bb;
  y2 = y2 > 0.0 ? y2 : 0.2 * y2;
  double mxv = fmax(y1, y2);
  x2d[i] = mxv;
  out448[(size_t)p*448 + C1 + o] = (float)mxv;
}

// ---- pack w3 -> bf16 MFMA-B-frag layout (ONCE):
// wpk[nt*256 + ks*64 + lane] = 8 bf16 of w[oc][ks*32 + g*8 + e],
// oc = nt*16 + (lane&15), g = lane>>4. ----
__global__ __launch_bounds__(256) void wpack_kernel(const float* __restrict__ w,
                                                    bf16x8* __restrict__ wpk) {
  int idx = blockIdx.x * 256 + threadIdx.x;   // grid = 16 -> 4096 frags
  int lane = idx & 63;
  int ks = (idx >> 6) & 3;
  int nt = idx >> 8;
  int oc = nt*16 + (lane & 15);
  int g = lane >> 4;
  const float* src = w + (size_t)oc * (2*C2) + ks*32 + g*8;
  bf16x8 pk;
  #pragma unroll
  for (int e = 0; e < 8; ++e) {
    __hip_bfloat16 hb = __float2bfloat16(src[e]);
    pk[e] = *reinterpret_cast<short*>(&hb);
  }
  wpk[idx] = pk;
}

// ---- base[p,o] = sum_c (w[o,C2+c]-w[o,c]) * x2f[p,c]  (value path, f32 GEMM) ----
__global__ __launch_bounds__(256) void base_kernel(const float* __restrict__ x2f,
                                                   const float* __restrict__ w,
                                                   float* __restrict__ baseB) {
  int to = blockIdx.x * 64;   // o-tile (grid.x = C3/64 = 4)
  int tp = blockIdx.y * 64;   // p-tile (grid.y = B*N/64 = 256)
  int tid = threadIdx.x;
  int tr = tid >> 4, tc = tid & 15;
  __shared__ float A[64][9], Bm[64][9];
  float acc[4][4];
  #pragma unroll
  for (int u = 0; u < 4; ++u)
    #pragma unroll
    for (int v = 0; v < 4; ++v) acc[u][v] = 0.f;
  for (int c0 = 0; c0 < C2; c0 += 8) {
    for (int i = tid; i < 512; i += 256) {
      int r = i >> 3, c = i & 7;
      A[r][c]  = x2f[(size_t)(tp + r)*C2 + c0 + c];
      const float* wr = w + (size_t)(to + r) * (2*C2);
      Bm[r][c] = wr[C2 + c0 + c] - wr[c0 + c];
    }
    __syncthreads();
    #pragma unroll
    for (int c = 0; c < 8; ++c) {
      float a[4], bv[4];
      #pragma unroll
      for (int u = 0; u < 4; ++u) a[u] = A[tr*4 + u][c];
      #pragma unroll
      for (int v = 0; v < 4; ++v) bv[v] = Bm[tc*4 + v][c];
      #pragma unroll
      for (int u = 0; u < 4; ++u)
        #pragma unroll
        for (int v = 0; v < 4; ++v) acc[u][v] = fmaf(a[u], bv[v], acc[u][v]);
    }
    __syncthreads();
  }
  #pragma unroll
  for (int u = 0; u < 4; ++u) {
    #pragma unroll
    for (int v = 0; v < 4; ++v)
      baseB[(size_t)(tp + tr*4 + u)*C3 + to + tc*4 + v] = acc[u][v];
  }
}

// ---- conv3 pass0 MFMA v3: pre-packed B-frags + precomputed base.
// D[kn,o] via mfma_f32_16x16x32_bf16 (layout m89-verified, r20-validated).
// xj staged bf16 in LDS with slot^(row&15) swizzle (2-way-free frag reads). ----
__global__ __launch_bounds__(256, 1) void conv3_p0_mfma(
    const float* __restrict__ x2f, const int* __restrict__ idx,
    const bf16x8* __restrict__ wpk, const float* __restrict__ baseB,
    double* __restrict__ sS, double* __restrict__ sQ,
    float* __restrict__ hmx3, float* __restrict__ hmn3) {
  int p = blockIdx.x;
  int tid = threadIdx.x;
  int lane = tid & 63;
  int wv = tid >> 6;
  int b = p >> 11;
  __shared__ float4 xjB4[32 * 16];   // bf16 [kn][c], 16B slots, slot^(row&15)
  __shared__ int    jidx[K];
  if (tid < K) jidx[tid] = idx[(size_t)p*K + tid];
  __syncthreads();
  #pragma unroll 1
  for (int i = tid; i < 320; i += 256) {
    int row = i >> 4, slot = i & 15;
    const float* src = x2f + ((size_t)b*N + jidx[row])*C2 + slot*8;
    bf16x8 pk;
    #pragma unroll
    for (int e = 0; e < 8; ++e) {
      __hip_bfloat16 hb = __float2bfloat16(src[e]);
      pk[e] = *reinterpret_cast<short*>(&hb);
    }
    *reinterpret_cast<bf16x8*>(&xjB4[row*16 + (slot ^ (row & 15))]) = pk;
  }
  __syncthreads();
  bf16x8 afrag[2][4];
  #pragma unroll
  for (int mt = 0; mt < 2; ++mt) {
    #pragma unroll
    for (int ks = 0; ks < 4; ++ks) {
      int row = mt*16 + (lane & 15);
      int slot = ks*4 + (lane >> 4);
      afrag[mt][ks] = *reinterpret_cast<const bf16x8*>(&xjB4[row*16 + (slot ^ (row & 15))]);
    }
  }
  int slice = p & (NSLICE - 1);
  int g = lane >> 4;
  #pragma unroll 1
  for (int nt = wv; nt < 16; nt += 4) {
    int oc = nt*16 + (lane & 15);
    f32x4 acc0 = {0.f, 0.f, 0.f, 0.f};
    f32x4 acc1 = {0.f, 0.f, 0.f, 0.f};
    #pragma unroll
    for (int ks = 0; ks < 4; ++ks) {
      bf16x8 bw = wpk[nt*256 + ks*64 + lane];   // coalesced 16B/lane
      acc0 = __builtin_amdgcn_mfma_f32_16x16x32_bf16(afrag[0][ks], bw, acc0, 0, 0, 0);
      acc1 = __builtin_amdgcn_mfma_f32_16x16x32_bf16(afrag[1][ks], bw, acc1, 0, 0, 0);
    }
    float bs = baseB[(size_t)p*C3 + oc];
    float s = 0.f, q = 0.f, mxv = -INFINITY, mnv = INFINITY;
    #pragma unroll
    for (int r = 0; r < 4; ++r) {
      float h = bs + acc0[r];
      s += h; q += h*h;
      mxv = fmaxf(mxv, h); mnv = fminf(mnv, h);
    }
    if (g == 0) {
      #pragma unroll
      for (int r = 0; r < 4; ++r) {
        float h = bs + acc1[r];
        s += h; q += h*h;
        mxv = fmaxf(mxv, h); mnv = fminf(mnv, h);
      }
    }
    #pragma unroll
    for (int off = 16; off <= 32; off <<= 1) {
      s += __shfl_xor(s, off, 64);
      q += __shfl_xor(q, off, 64);
      mxv = fmaxf(mxv, __shfl_xor(mxv, off, 64));
      mnv = fminf(mnv, __shfl_xor(mnv, off, 64));
    }
    if (g == 0) {
      hmx3[(size_t)p*C3 + oc] = mxv;
      hmn3[(size_t)p*C3 + oc] = mnv;
      atomicAdd(&sS[slice*C3 + oc], (double)s);
      atomicAdd(&sQ[slice*C3 + oc], (double)q);
    }
  }
}

// ---- conv3 pass1 (light): BN+LReLU at extremes, fmax -> out ----
__global__ __launch_bounds__(256) void conv3_p1_light(
    const float* __restrict__ hmx3, const float* __restrict__ hmn3,
    const double* __restrict__ mid, const float* __restrict__ gam,
    const float* __restrict__ bet, float* __restrict__ out448) {
  int i = blockIdx.x * 256 + threadIdx.x;   // grid = B*N*C3/256
  int p = i >> 8, o = i & 255;
  float m = (float)mid[o], is = (float)mid[C3 + o];
  float g = gam[o], bb = bet[o];
  float y1 = (hmx3[i] - m) * is * g + bb;
  y1 = y1 > 0.f ? y1 : 0.2f * y1;
  float y2 = (hmn3[i] - m) * is * g + bb;
  y2 = y2 > 0.f ? y2 : 0.2f * y2;
  out448[(size_t)p*448 + C1 + C2 + o] = fmaxf(y1, y2);
}

// ---- finalize BN stats (f64) ----
__global__ void finalize_stats(const double* __restrict__ sS, const double* __restrict__ sQ,
                               double* __restrict__ mid, int C) {
  int o = threadIdx.x;
  if (o >= C) return;
  double s = 0., q = 0.;
  for (int i = 0; i < NSLICE; ++i) { s += sS[i*C3 + o]; q += sQ[i*C3 + o]; }
  double m = s / COUNT;
  double v = q / COUNT - m*m;
  mid[o] = m;
  mid[C3 + o] = 1.0 / sqrt(v + BNEPS);
}

} // namespace

extern "C" void kernel_launch(void* const* d_in, const int* in_sizes, int n_in,
                              void* d_out, int out_size, void* d_ws, size_t ws_size,
                              hipStream_t stream) {
  (void)in_sizes; (void)n_in; (void)out_size; (void)ws_size;
  const float* x   = (const float*)d_in[0];
  const float* nrm = (const float*)d_in[1];
  const float* w1  = (const float*)d_in[2];
  const float* g1  = (const float*)d_in[3];
  const float* b1  = (const float*)d_in[4];
  const float* w2  = (const float*)d_in[5];
  const float* g2  = (const float*)d_in[6];
  const float* b2  = (const float*)d_in[7];
  const float* w3  = (const float*)d_in[8];
  const float* g3  = (const float*)d_in[9];
  const float* b3  = (const float*)d_in[10];
  float* out = (float*)d_out;
  char*  ws  = (char*)d_ws;

  int*    idx1 = (int*)(ws + OFF_IDX1);
  int*    idx2 = (int*)(ws + OFF_IDX2);
  double* x1d  = (double*)(ws + OFF_X1D);
  double* x2d  = (double*)(ws + OFF_X2D);
  double* sS   = (double*)(ws + OFF_STATS);
  double* sQ   = sS + (size_t)NSLICE * C3;
  double* mid  = (double*)(ws + OFF_MI);
  float*  x2f  = (float*)(ws + OFF_X2F);
  float*  xx2f = (float*)(ws + OFF_XX2F);
  bf16x8* wpk  = (bf16x8*)(ws + OFF_WPK);
  char*   big  = ws + OFF_BIG;
  double* hmx1 = (double*)big;                                   // l1_p0..p1
  double* hmn1 = hmx1 + (size_t)B*N*C1;
  double* hmx2 = (double*)big;                                   // conv2_p0..p1
  double* hmn2 = hmx2 + (size_t)B*N*C2;
  float*  dist = (float*)big;                                    // dist..knn_feat
  float*  hmx3 = (float*)big;                                    // conv3_p0..p1
  float*  hmn3 = hmx3 + (size_t)B*N*C3;
  float*  baseB = hmn3 + (size_t)B*N*C3;

  float* outR1 = out + (size_t)B * N * 448;
  float* outR2 = outR1 + (size_t)B * N * 9;

  // w3 bf16 frag pack (once; independent of everything else)
  wpack_kernel<<<16, 256, 0, stream>>>(w3, wpk);

  // kNN1 — numpy-f32-faithful values, wave-parallel selection
  knn_xyz_wave<<<B*N/4, 256, 0, stream>>>(x, idx1);

  // layer 1: geometry+conv once (bit-frozen chain) + extremes; light BN finish
  hipMemsetAsync(sS, 0, (size_t)2*NSLICE*C3*sizeof(double), stream);
  l1_p0<<<B*N, 64, 0, stream>>>(x, nrm, w1, idx1, sS, sQ, hmx1, hmn1, outR1, outR2);
  finalize_stats<<<1, C3, 0, stream>>>(sS, sQ, mid, C1);
  l1_p1_light<<<B*N*C1/256, 256, 0, stream>>>(hmx1, hmn1, mid, g1, b1, x1d, out);

  // layer 2: conv once (bit-frozen core) + extremes; light BN finish
  hipMemsetAsync(sS, 0, (size_t)2*NSLICE*C3*sizeof(double), stream);
  conv2_p0<<<B*N, 128, 0, stream>>>(x1d, idx1, w2, sS, sQ, hmx2, hmn2);
  finalize_stats<<<1, C3, 0, stream>>>(sS, sQ, mid, C2);
  conv2_p1_light<<<B*N*C2/256, 256, 0, stream>>>(hmx2, hmn2, mid, g2, b2, x2d, out);

  // kNN2 — numpy-f32-faithful, all batches fused; wave-parallel coalesced top-k
  xx2f_kernel<<<B*N/64, 64, 0, stream>>>(x2d, x2f, xx2f);
  dist_f32_kernel<<<dim3(N/64, N/64, B), 256, 0, stream>>>(x2f, xx2f, dist);
  knn_feat_wave<<<B*N/4, 256, 0, stream>>>(dist, idx2);

  // layer 3: base GEMM (dist dead) + MFMA conv + extremes; light BN finish
  base_kernel<<<dim3(C3/64, B*N/64), 256, 0, stream>>>(x2f, w3, baseB);
  hipMemsetAsync(sS, 0, (size_t)2*NSLICE*C3*sizeof(double), stream);
  conv3_p0_mfma<<<B*N, 256, 0, stream>>>(x2f, idx2, wpk, baseB, sS, sQ, hmx3, hmn3);
  finalize_stats<<<1, C3, 0, stream>>>(sS, sQ, mid, C3);
  conv3_p1_light<<<B*N*C3/256, 256, 0, stream>>>(hmx3, hmn3, mid, g3, b3, out);
}

// Round 22
// 791.291 us; speedup vs baseline: 1.9637x; 1.0637x over previous
//
#include <hip/hip_runtime.h>
#include <hip/hip_bf16.h>
#include <math.h>

namespace {

constexpr int B  = 8;
constexpr int N  = 2048;     // power of two: n = p & 2047, b = p >> 11
constexpr int K  = 20;
constexpr int C1 = 64, C2 = 128, C3 = 256;
constexpr int NSLICE = 64;
constexpr double COUNT = 327680.0;   // B*N*K
constexpr double BNEPS = 1e-5;

// ---- workspace layout (bytes) ----
constexpr size_t OFF_IDX1  = 0;                                  // B*N*K int
constexpr size_t OFF_IDX2  = OFF_IDX1 + (size_t)B*N*K*4;         // B*N*K int
constexpr size_t OFF_X1D   = OFF_IDX2 + (size_t)B*N*K*4;         // B*N*C1 f64
constexpr size_t OFF_X2D   = OFF_X1D  + (size_t)B*N*C1*8;        // B*N*C2 f64
constexpr size_t OFF_STATS = OFF_X2D  + (size_t)B*N*C2*8;        // 2*NSLICE*C3 f64
constexpr size_t OFF_MI    = OFF_STATS+ (size_t)2*NSLICE*C3*8;   // 2*C3 f64
constexpr size_t OFF_X2F   = OFF_MI   + 4096;                    // B*N*C2 f32
constexpr size_t OFF_XX2F  = OFF_X2F  + (size_t)B*N*C2*4;        // B*N f32
constexpr size_t OFF_WPK   = OFF_XX2F + (size_t)B*N*4;           // 16*4*64 bf16x8 = 64KB
constexpr size_t OFF_BIG   = OFF_WPK  + 65536;                   // shared big region
// big region, sequential lifetimes (within proven footprint):
//   {hmax1,hmin1 f64} -> {hmax2,hmin2,base2 f64: 3 x 16.8 MB}
//   -> dist f32 (134.2 MB) -> {hmax3,hmin3,baseB f32: 3 x 16.8 MB}

typedef short  bf16x8 __attribute__((ext_vector_type(8)));
typedef float  f32x4  __attribute__((ext_vector_type(4)));

// ---- strict-rounding f32 helpers (block FMA contraction / reassociation) ----
__device__ __forceinline__ float fmul32(float a, float b){ return __fmul_rn(a,b); }
__device__ __forceinline__ float fadd32(float a, float b){ return __fadd_rn(a,b); }
__device__ __forceinline__ float fsub32(float a, float b){ return __fsub_rn(a,b); }

// ---- kNN on 3-D coords, numpy-f32-faithful values, wave-parallel top-20 ----
__global__ __launch_bounds__(256) void knn_xyz_wave(const float* __restrict__ x,
                                                    int* __restrict__ idxo) {
  int row  = blockIdx.x * 4 + (threadIdx.x >> 6);   // grid = B*N/4
  int lane = threadIdx.x & 63;
  int b = row >> 11, n = row & (N - 1);
  const float* xb = x + (size_t)b * N * 3;
  float xi0 = xb[(size_t)n*3], xi1 = xb[(size_t)n*3+1], xi2 = xb[(size_t)n*3+2];
  float xxi = fadd32(fadd32(fmul32(xi0,xi0), fmul32(xi1,xi1)), fmul32(xi2,xi2));
  float vals[32];
  #pragma unroll
  for (int t = 0; t < 32; ++t) {
    int j = lane + (t << 6);
    float a = xb[(size_t)j*3], c = xb[(size_t)j*3+1], d = xb[(size_t)j*3+2];
    float xxj   = fadd32(fadd32(fmul32(a,a), fmul32(c,c)), fmul32(d,d));
    float inner = fadd32(fadd32(fmul32(xi0,a), fmul32(xi1,c)), fmul32(xi2,d));
    vals[t] = fsub32(fsub32(fmul32(2.f, inner), xxi), xxj);
  }
  int* out = idxo + (size_t)row * K;
  for (int sel = 0; sel < K; ++sel) {
    float best = -INFINITY; int bt = 0;
    #pragma unroll
    for (int t = 0; t < 32; ++t)
      if (vals[t] > best) { best = vals[t]; bt = t; }
    int bcol = lane + (bt << 6);
    #pragma unroll
    for (int off = 32; off >= 1; off >>= 1) {
      float ov = __shfl_xor(best, off, 64);
      int   oc = __shfl_xor(bcol, off, 64);
      if (ov > best || (ov == best && oc < bcol)) { best = ov; bcol = oc; }
    }
    if (lane == 0) out[sel] = bcol;
    int kill = ((bcol & 63) == lane) ? (bcol >> 6) : 32;
    #pragma unroll
    for (int t = 0; t < 32; ++t) if (t == kill) vals[t] = -INFINITY;
  }
}

// ---- x2 -> f32 copy + numpy pairwise(n=128) sum of squares (BIT-FROZEN) ----
__global__ __launch_bounds__(64) void xx2f_kernel(const double* __restrict__ x2d,
                                                  float* __restrict__ x2f,
                                                  float* __restrict__ xx2f) {
  int row = blockIdx.x * 64 + threadIdx.x;   // grid = B*N/64
  const double* src = x2d + (size_t)row * C2;
  float* dst = x2f + (size_t)row * C2;
  float sq[C2];
  #pragma unroll 8
  for (int c = 0; c < C2; ++c) {
    float v = (float)src[c];
    dst[c] = v;
    sq[c] = fmul32(v, v);
  }
  float r0=sq[0], r1=sq[1], r2=sq[2], r3=sq[3], r4=sq[4], r5=sq[5], r6=sq[6], r7=sq[7];
  #pragma unroll
  for (int i = 8; i < 128; i += 8) {
    r0 = fadd32(r0, sq[i+0]); r1 = fadd32(r1, sq[i+1]);
    r2 = fadd32(r2, sq[i+2]); r3 = fadd32(r3, sq[i+3]);
    r4 = fadd32(r4, sq[i+4]); r5 = fadd32(r5, sq[i+5]);
    r6 = fadd32(r6, sq[i+6]); r7 = fadd32(r7, sq[i+7]);
  }
  xx2f[row] = fadd32(fadd32(fadd32(r0,r1), fadd32(r2,r3)),
                     fadd32(fadd32(r4,r5), fadd32(r6,r7)));
}

// ---- all-batch neg-distance matrix, f32 sequential (BIT-FROZEN inner) ----
__global__ __launch_bounds__(256) void dist_f32_kernel(const float* __restrict__ x2f,
                                                       const float* __restrict__ xx2f,
                                                       float* __restrict__ dist) {
  int bz = blockIdx.z;
  const float* x2b  = x2f  + (size_t)bz * N * C2;
  const float* xx2b = xx2f + (size_t)bz * N;
  float* db = dist + (size_t)bz * N * N;
  int ti = blockIdx.y * 64;
  int tj = blockIdx.x * 64;
  int tid = threadIdx.x;
  int tr = tid >> 4, tc = tid & 15;
  __shared__ float A[64][9], Bm[64][9];
  float acc[4][4];
  #pragma unroll
  for (int u = 0; u < 4; ++u)
    #pragma unroll
    for (int v = 0; v < 4; ++v) acc[u][v] = 0.f;
  for (int c0 = 0; c0 < C2; c0 += 8) {
    for (int i = tid; i < 512; i += 256) {
      int r = i >> 3, c = i & 7;
      A[r][c]  = x2b[(size_t)(ti + r)*C2 + c0 + c];
      Bm[r][c] = x2b[(size_t)(tj + r)*C2 + c0 + c];
    }
    __syncthreads();
    #pragma unroll
    for (int c = 0; c < 8; ++c) {       // ascending c: exact sequential order
      float a[4], bv[4];
      #pragma unroll
      for (int u = 0; u < 4; ++u) a[u] = A[tr*4 + u][c];
      #pragma unroll
      for (int v = 0; v < 4; ++v) bv[v] = Bm[tc*4 + v][c];
      #pragma unroll
      for (int u = 0; u < 4; ++u)
        #pragma unroll
        for (int v = 0; v < 4; ++v)
          acc[u][v] = fadd32(acc[u][v], fmul32(a[u], bv[v]));
    }
    __syncthreads();
  }
  #pragma unroll
  for (int u = 0; u < 4; ++u) {
    int i = ti + tr*4 + u;
    float xxi = xx2b[i];
    #pragma unroll
    for (int v = 0; v < 4; ++v) {
      int j = tj + tc*4 + v;
      db[(size_t)i*N + j] = fsub32(fsub32(fmul32(2.f, acc[u][v]), xxi), xx2b[j]);
    }
  }
}

// ---- wave-parallel top-20 on frozen dist values (coalesced reads) ----
__global__ __launch_bounds__(256) void knn_feat_wave(const float* __restrict__ dist,
                                                     int* __restrict__ idxo) {
  int row  = blockIdx.x * 4 + (threadIdx.x >> 6);   // grid = B*N/4
  int lane = threadIdx.x & 63;
  const float* dr = dist + (size_t)row * N;
  float vals[32];
  #pragma unroll
  for (int t = 0; t < 32; ++t) vals[t] = dr[lane + (t << 6)];   // coalesced
  int* out = idxo + (size_t)row * K;
  for (int sel = 0; sel < K; ++sel) {
    float best = -INFINITY; int bt = 0;
    #pragma unroll
    for (int t = 0; t < 32; ++t)
      if (vals[t] > best) { best = vals[t]; bt = t; }
    int bcol = lane + (bt << 6);
    #pragma unroll
    for (int off = 32; off >= 1; off >>= 1) {
      float ov = __shfl_xor(best, off, 64);
      int   oc = __shfl_xor(bcol, off, 64);
      if (ov > best || (ov == best && oc < bcol)) { best = ov; bcol = oc; }
    }
    if (lane == 0) out[sel] = bcol;
    int kill = ((bcol & 63) == lane) ? (bcol >> 6) : 32;
    #pragma unroll
    for (int t = 0; t < 32; ++t) if (t == kill) vals[t] = -INFINITY;
  }
}

// ---- layer 1 pass0: geometry + conv1 (frozen chain) + stats
// + f64 hmax/hmin store; writes R1/R2. ----
__global__ __launch_bounds__(64) void l1_p0(
    const float* __restrict__ x, const float* __restrict__ nrm,
    const float* __restrict__ w1, const int* __restrict__ idx1,
    double* __restrict__ sS, double* __restrict__ sQ,
    double* __restrict__ hmx1, double* __restrict__ hmn1,
    float* __restrict__ outR1, float* __restrict__ outR2) {
  int p = blockIdx.x;
  int tid = threadIdx.x;
  int b = p >> 11, n = p & (N - 1);
  __shared__ float  wl[C1 * 9];
  __shared__ double rotd[K][3];
  __shared__ double fld[K][9];
  for (int i = tid; i < C1 * 9; i += 64) wl[i] = w1[i];
  const float* xb = x + (size_t)b * N * 3;
  double nx = nrm[(size_t)p*3], ny = nrm[(size_t)p*3+1], nz = nrm[(size_t)p*3+2];
  double vx = ny, vy = -nx;
  double s = 1.0 / fmax(1.0 + nz, 1e-8);
  double vxy = vx * vy;
  double R1v[9];
  R1v[0] = 1.0 - s*(vy*vy); R1v[1] = s*vxy;           R1v[2] = vy;
  R1v[3] = s*vxy;           R1v[4] = 1.0 - s*(vx*vx); R1v[5] = -vx;
  R1v[6] = -vy;             R1v[7] = vx;              R1v[8] = 1.0 - s*(vx*vx + vy*vy);
  double xi0 = xb[(size_t)n*3], xi1 = xb[(size_t)n*3+1], xi2 = xb[(size_t)n*3+2];
  if (tid < K) {
    int j = idx1[(size_t)p*K + tid];
    double d0 = (double)xb[(size_t)j*3]   - xi0;
    double d1 = (double)xb[(size_t)j*3+1] - xi1;
    double d2 = (double)xb[(size_t)j*3+2] - xi2;
    rotd[tid][0] = R1v[0]*d0 + R1v[1]*d1 + R1v[2]*d2;
    rotd[tid][1] = R1v[3]*d0 + R1v[4]*d1 + R1v[5]*d2;
    rotd[tid][2] = R1v[6]*d0 + R1v[7]*d1 + R1v[8]*d2;
  }
  __syncthreads();
  double mx = 0.0, my = 0.0;
  #pragma unroll
  for (int k = 0; k < K; ++k) { mx += rotd[k][0]; my += rotd[k][1]; }
  mx /= 20.0; my /= 20.0;
  double r = sqrt(mx*mx + my*my);
  double ct = 1.0, st = 0.0;
  if (r > 0.0) { ct = mx / r; st = my / r; }   // cos/sin of atan2(my,mx)
  if (tid < K) {
    double r0 = rotd[tid][0], r1 = rotd[tid][1], r2 = rotd[tid][2];
    double a0 = ct*r0 + st*r1;
    double a1 = ct*r1 - st*r0;
    fld[tid][0] = a0;  fld[tid][1] = a1;   fld[tid][2] = r2;
    fld[tid][3] = a0;  fld[tid][4] = -a1;  fld[tid][5] = r2;   // xz-mirror
    fld[tid][6] = xi0; fld[tid][7] = xi1;  fld[tid][8] = xi2;  // x_rep
  }
  if (tid == 0) {
    float* o1 = outR1 + (size_t)p * 9;
    #pragma unroll
    for (int i = 0; i < 9; ++i) o1[i] = (float)R1v[i];
    float* o2 = outR2 + (size_t)p * 9;
    o2[0] = (float)ct;  o2[1] = (float)st; o2[2] = 0.f;
    o2[3] = (float)-st; o2[4] = (float)ct; o2[5] = 0.f;
    o2[6] = 0.f;        o2[7] = 0.f;       o2[8] = 1.f;
  }
  __syncthreads();
  int o = tid;
  double sum = 0., sq = 0., hmx = -INFINITY, hmn = INFINITY;
  #pragma unroll
  for (int k = 0; k < K; ++k) {
    double h = 0.;
    #pragma unroll
    for (int c = 0; c < 9; ++c) h = fma((double)wl[o*9 + c], fld[k][c], h);
    sum += h; sq += h*h;
    hmx = fmax(hmx, h); hmn = fmin(hmn, h);
  }
  hmx1[(size_t)p*C1 + o] = hmx;
  hmn1[(size_t)p*C1 + o] = hmn;
  int slice = p & (NSLICE - 1);
  atomicAdd(&sS[slice*C3 + o], sum);
  atomicAdd(&sQ[slice*C3 + o], sq);
}

// ---- layer 1 pass1 (light): BN+LReLU at h extremes ----
__global__ __launch_bounds__(256) void l1_p1_light(
    const double* __restrict__ hmx1, const double* __restrict__ hmn1,
    const double* __restrict__ mid, const float* __restrict__ g1,
    const float* __restrict__ b1,
    double* __restrict__ x1d, float* __restrict__ out448) {
  int i = blockIdx.x * 256 + threadIdx.x;   // grid = B*N*C1/256
  int p = i >> 6, o = i & 63;
  double m = mid[o], is = mid[C3 + o];
  double g = g1[o], bb = b1[o];
  double y1 = ((hmx1[i] - m) * is) * g + bb;
  y1 = y1 > 0.0 ? y1 : 0.2 * y1;
  double y2 = ((hmn1[i] - m) * is) * g + bb;
  y2 = y2 > 0.0 ? y2 : 0.2 * y2;
  double mxv = fmax(y1, y2);
  x1d[i] = mxv;
  out448[(size_t)p*448 + o] = (float)mxv;
}

// ---- base2[p,o] = sum_c (w2[o,C1+c]-w2[o,c]) * x1d[p,c]   (f64 GEMM) ----
__global__ __launch_bounds__(256) void base2_kernel(const double* __restrict__ x1d,
                                                    const float* __restrict__ w,
                                                    double* __restrict__ base2B) {
  int to = blockIdx.x * 64;   // o-tile (grid.x = C2/64 = 2)
  int tp = blockIdx.y * 64;   // p-tile (grid.y = B*N/64 = 256)
  int tid = threadIdx.x;
  int tr = tid >> 4, tc = tid & 15;
  __shared__ double A[64][9], Bm[64][9];
  double acc[4][4];
  #pragma unroll
  for (int u = 0; u < 4; ++u)
    #pragma unroll
    for (int v = 0; v < 4; ++v) acc[u][v] = 0.;
  for (int c0 = 0; c0 < C1; c0 += 8) {
    for (int i = tid; i < 512; i += 256) {
      int r = i >> 3, c = i & 7;
      A[r][c]  = x1d[(size_t)(tp + r)*C1 + c0 + c];
      const float* wr = w + (size_t)(to + r) * (2*C1);
      Bm[r][c] = (double)wr[C1 + c0 + c] - (double)wr[c0 + c];
    }
    __syncthreads();
    #pragma unroll
    for (int c = 0; c < 8; ++c) {
      double a[4], bv[4];
      #pragma unroll
      for (int u = 0; u < 4; ++u) a[u] = A[tr*4 + u][c];
      #pragma unroll
      for (int v = 0; v < 4; ++v) bv[v] = Bm[tc*4 + v][c];
      #pragma unroll
      for (int u = 0; u < 4; ++u)
        #pragma unroll
        for (int v = 0; v < 4; ++v) acc[u][v] = fma(a[u], bv[v], acc[u][v]);
    }
    __syncthreads();
  }
  #pragma unroll
  for (int u = 0; u < 4; ++u) {
    #pragma unroll
    for (int v = 0; v < 4; ++v)
      base2B[(size_t)(tp + tr*4 + u)*C2 + to + tc*4 + v] = acc[u][v];
  }
}

// ---- conv2 pass0 v2 (r6-proven folded algebra): h = sum_c w[c]*xj[c] + base2.
// Gather-GEMM only (phase2 eliminated); stats + hmax/hmin. f64 noise vs the
// unfolded chain is selection-safe (r6<->r7 identical outputs). ----
__global__ __launch_bounds__(128, 1) void conv2_p0(
    const double* __restrict__ x1d, const int* __restrict__ idx,
    const float* __restrict__ w, const double* __restrict__ base2B,
    double* __restrict__ sS, double* __restrict__ sQ,
    double* __restrict__ hmx2, double* __restrict__ hmn2) {
  int p = blockIdx.x;
  int tid = threadIdx.x;
  int b = p >> 11;
  __shared__ double xjL[K][C1];
  __shared__ int jidx[K];
  if (tid < K) jidx[tid] = idx[(size_t)p*K + tid];
  __syncthreads();
  #pragma unroll 1
  for (int i = tid; i < K*C1; i += 128) {
    int k = i >> 6, c = i & 63;
    xjL[k][c] = x1d[((size_t)b*N + jidx[k])*C1 + c];
  }
  __syncthreads();
  const float* wr = w + (size_t)tid * (2*C1);
  double acc[K];
  #pragma unroll
  for (int k = 0; k < K; ++k) acc[k] = 0.0;
  #pragma unroll
  for (int c0 = 0; c0 < C1; c0 += 16) {
    double wd[16];
    #pragma unroll
    for (int i = 0; i < 16; ++i) wd[i] = (double)wr[c0+i];
    #pragma unroll
    for (int k = 0; k < K; ++k) {
      #pragma unroll
      for (int i = 0; i < 16; ++i) acc[k] = fma(wd[i], xjL[k][c0+i], acc[k]);
    }
  }
  double base = base2B[(size_t)p*C2 + tid];
  double sum = 0., sq = 0., hmx = -INFINITY, hmn = INFINITY;
  #pragma unroll
  for (int k = 0; k < K; ++k) {
    double h = acc[k] + base;
    sum += h; sq += h*h;
    hmx = fmax(hmx, h); hmn = fmin(hmn, h);
  }
  hmx2[(size_t)p*C2 + tid] = hmx;
  hmn2[(size_t)p*C2 + tid] = hmn;
  int slice = p & (NSLICE - 1);
  atomicAdd(&sS[slice*C3 + tid], sum);
  atomicAdd(&sQ[slice*C3 + tid], sq);
}

// ---- conv2 pass1 (light): BN+LReLU at h extremes (monotone => exact) ----
__global__ __launch_bounds__(256) void conv2_p1_light(
    const double* __restrict__ hmx2, const double* __restrict__ hmn2,
    const double* __restrict__ mid, const float* __restrict__ gam,
    const float* __restrict__ bet,
    double* __restrict__ x2d, float* __restrict__ out448) {
  int i = blockIdx.x * 256 + threadIdx.x;   // grid = B*N*C2/256
  int p = i >> 7, o = i & 127;
  double m = mid[o], is = mid[C3 + o];
  double g = gam[o], bb = bet[o];
  double y1 = ((hmx2[i] - m) * is) * g + bb;
  y1 = y1 > 0.0 ? y1 : 0.2 * y1;
  double y2 = ((hmn2[i] - m) * is) * g + bb;
  y2 = y2 > 0.0 ? y2 : 0.2 * y2;
  double mxv = fmax(y1, y2);
  x2d[i] = mxv;
  out448[(size_t)p*448 + C1 + o] = (float)mxv;
}

// ---- pack w3 -> bf16 MFMA-B-frag layout (ONCE) ----
__global__ __launch_bounds__(256) void wpack_kernel(const float* __restrict__ w,
                                                    bf16x8* __restrict__ wpk) {
  int idx = blockIdx.x * 256 + threadIdx.x;   // grid = 16 -> 4096 frags
  int lane = idx & 63;
  int ks = (idx >> 6) & 3;
  int nt = idx >> 8;
  int oc = nt*16 + (lane & 15);
  int g = lane >> 4;
  const float* src = w + (size_t)oc * (2*C2) + ks*32 + g*8;
  bf16x8 pk;
  #pragma unroll
  for (int e = 0; e < 8; ++e) {
    __hip_bfloat16 hb = __float2bfloat16(src[e]);
    pk[e] = *reinterpret_cast<short*>(&hb);
  }
  wpk[idx] = pk;
}

// ---- base[p,o] = sum_c (w[o,C2+c]-w[o,c]) * x2f[p,c]  (value path, f32 GEMM) ----
__global__ __launch_bounds__(256) void base_kernel(const float* __restrict__ x2f,
                                                   const float* __restrict__ w,
                                                   float* __restrict__ baseB) {
  int to = blockIdx.x * 64;   // o-tile (grid.x = C3/64 = 4)
  int tp = blockIdx.y * 64;   // p-tile (grid.y = B*N/64 = 256)
  int tid = threadIdx.x;
  int tr = tid >> 4, tc = tid & 15;
  __shared__ float A[64][9], Bm[64][9];
  float acc[4][4];
  #pragma unroll
  for (int u = 0; u < 4; ++u)
    #pragma unroll
    for (int v = 0; v < 4; ++v) acc[u][v] = 0.f;
  for (int c0 = 0; c0 < C2; c0 += 8) {
    for (int i = tid; i < 512; i += 256) {
      int r = i >> 3, c = i & 7;
      A[r][c]  = x2f[(size_t)(tp + r)*C2 + c0 + c];
      const float* wr = w + (size_t)(to + r) * (2*C2);
      Bm[r][c] = wr[C2 + c0 + c] - wr[c0 + c];
    }
    __syncthreads();
    #pragma unroll
    for (int c = 0; c < 8; ++c) {
      float a[4], bv[4];
      #pragma unroll
      for (int u = 0; u < 4; ++u) a[u] = A[tr*4 + u][c];
      #pragma unroll
      for (int v = 0; v < 4; ++v) bv[v] = Bm[tc*4 + v][c];
      #pragma unroll
      for (int u = 0; u < 4; ++u)
        #pragma unroll
        for (int v = 0; v < 4; ++v) acc[u][v] = fmaf(a[u], bv[v], acc[u][v]);
    }
    __syncthreads();
  }
  #pragma unroll
  for (int u = 0; u < 4; ++u) {
    #pragma unroll
    for (int v = 0; v < 4; ++v)
      baseB[(size_t)(tp + tr*4 + u)*C3 + to + tc*4 + v] = acc[u][v];
  }
}

// ---- conv3 pass0 MFMA (r21-proven): pre-packed B-frags + precomputed base ----
__global__ __launch_bounds__(256, 1) void conv3_p0_mfma(
    const float* __restrict__ x2f, const int* __restrict__ idx,
    const bf16x8* __restrict__ wpk, const float* __restrict__ baseB,
    double* __restrict__ sS, double* __restrict__ sQ,
    float* __restrict__ hmx3, float* __restrict__ hmn3) {
  int p = blockIdx.x;
  int tid = threadIdx.x;
  int lane = tid & 63;
  int wv = tid >> 6;
  int b = p >> 11;
  __shared__ float4 xjB4[32 * 16];   // bf16 [kn][c], 16B slots, slot^(row&15)
  __shared__ int    jidx[K];
  if (tid < K) jidx[tid] = idx[(size_t)p*K + tid];
  __syncthreads();
  #pragma unroll 1
  for (int i = tid; i < 320; i += 256) {
    int row = i >> 4, slot = i & 15;
    const float* src = x2f + ((size_t)b*N + jidx[row])*C2 + slot*8;
    bf16x8 pk;
    #pragma unroll
    for (int e = 0; e < 8; ++e) {
      __hip_bfloat16 hb = __float2bfloat16(src[e]);
      pk[e] = *reinterpret_cast<short*>(&hb);
    }
    *reinterpret_cast<bf16x8*>(&xjB4[row*16 + (slot ^ (row & 15))]) = pk;
  }
  __syncthreads();
  bf16x8 afrag[2][4];
  #pragma unroll
  for (int mt = 0; mt < 2; ++mt) {
    #pragma unroll
    for (int ks = 0; ks < 4; ++ks) {
      int row = mt*16 + (lane & 15);
      int slot = ks*4 + (lane >> 4);
      afrag[mt][ks] = *reinterpret_cast<const bf16x8*>(&xjB4[row*16 + (slot ^ (row & 15))]);
    }
  }
  int slice = p & (NSLICE - 1);
  int g = lane >> 4;
  #pragma unroll 1
  for (int nt = wv; nt < 16; nt += 4) {
    int oc = nt*16 + (lane & 15);
    f32x4 acc0 = {0.f, 0.f, 0.f, 0.f};
    f32x4 acc1 = {0.f, 0.f, 0.f, 0.f};
    #pragma unroll
    for (int ks = 0; ks < 4; ++ks) {
      bf16x8 bw = wpk[nt*256 + ks*64 + lane];   // coalesced 16B/lane
      acc0 = __builtin_amdgcn_mfma_f32_16x16x32_bf16(afrag[0][ks], bw, acc0, 0, 0, 0);
      acc1 = __builtin_amdgcn_mfma_f32_16x16x32_bf16(afrag[1][ks], bw, acc1, 0, 0, 0);
    }
    float bs = baseB[(size_t)p*C3 + oc];
    float s = 0.f, q = 0.f, mxv = -INFINITY, mnv = INFINITY;
    #pragma unroll
    for (int r = 0; r < 4; ++r) {
      float h = bs + acc0[r];
      s += h; q += h*h;
      mxv = fmaxf(mxv, h); mnv = fminf(mnv, h);
    }
    if (g == 0) {
      #pragma unroll
      for (int r = 0; r < 4; ++r) {
        float h = bs + acc1[r];
        s += h; q += h*h;
        mxv = fmaxf(mxv, h); mnv = fminf(mnv, h);
      }
    }
    #pragma unroll
    for (int off = 16; off <= 32; off <<= 1) {
      s += __shfl_xor(s, off, 64);
      q += __shfl_xor(q, off, 64);
      mxv = fmaxf(mxv, __shfl_xor(mxv, off, 64));
      mnv = fminf(mnv, __shfl_xor(mnv, off, 64));
    }
    if (g == 0) {
      hmx3[(size_t)p*C3 + oc] = mxv;
      hmn3[(size_t)p*C3 + oc] = mnv;
      atomicAdd(&sS[slice*C3 + oc], (double)s);
      atomicAdd(&sQ[slice*C3 + oc], (double)q);
    }
  }
}

// ---- conv3 pass1 (light): BN+LReLU at extremes, fmax -> out ----
__global__ __launch_bounds__(256) void conv3_p1_light(
    const float* __restrict__ hmx3, const float* __restrict__ hmn3,
    const double* __restrict__ mid, const float* __restrict__ gam,
    const float* __restrict__ bet, float* __restrict__ out448) {
  int i = blockIdx.x * 256 + threadIdx.x;   // grid = B*N*C3/256
  int p = i >> 8, o = i & 255;
  float m = (float)mid[o], is = (float)mid[C3 + o];
  float g = gam[o], bb = bet[o];
  float y1 = (hmx3[i] - m) * is * g + bb;
  y1 = y1 > 0.f ? y1 : 0.2f * y1;
  float y2 = (hmn3[i] - m) * is * g + bb;
  y2 = y2 > 0.f ? y2 : 0.2f * y2;
  out448[(size_t)p*448 + C1 + C2 + o] = fmaxf(y1, y2);
}

// ---- finalize BN stats (f64) ----
__global__ void finalize_stats(const double* __restrict__ sS, const double* __restrict__ sQ,
                               double* __restrict__ mid, int C) {
  int o = threadIdx.x;
  if (o >= C) return;
  double s = 0., q = 0.;
  for (int i = 0; i < NSLICE; ++i) { s += sS[i*C3 + o]; q += sQ[i*C3 + o]; }
  double m = s / COUNT;
  double v = q / COUNT - m*m;
  mid[o] = m;
  mid[C3 + o] = 1.0 / sqrt(v + BNEPS);
}

} // namespace

extern "C" void kernel_launch(void* const* d_in, const int* in_sizes, int n_in,
                              void* d_out, int out_size, void* d_ws, size_t ws_size,
                              hipStream_t stream) {
  (void)in_sizes; (void)n_in; (void)out_size; (void)ws_size;
  const float* x   = (const float*)d_in[0];
  const float* nrm = (const float*)d_in[1];
  const float* w1  = (const float*)d_in[2];
  const float* g1  = (const float*)d_in[3];
  const float* b1  = (const float*)d_in[4];
  const float* w2  = (const float*)d_in[5];
  const float* g2  = (const float*)d_in[6];
  const float* b2  = (const float*)d_in[7];
  const float* w3  = (const float*)d_in[8];
  const float* g3  = (const float*)d_in[9];
  const float* b3  = (const float*)d_in[10];
  float* out = (float*)d_out;
  char*  ws  = (char*)d_ws;

  int*    idx1 = (int*)(ws + OFF_IDX1);
  int*    idx2 = (int*)(ws + OFF_IDX2);
  double* x1d  = (double*)(ws + OFF_X1D);
  double* x2d  = (double*)(ws + OFF_X2D);
  double* sS   = (double*)(ws + OFF_STATS);
  double* sQ   = sS + (size_t)NSLICE * C3;
  double* mid  = (double*)(ws + OFF_MI);
  float*  x2f  = (float*)(ws + OFF_X2F);
  float*  xx2f = (float*)(ws + OFF_XX2F);
  bf16x8* wpk  = (bf16x8*)(ws + OFF_WPK);
  char*   big  = ws + OFF_BIG;
  double* hmx1 = (double*)big;                                   // l1_p0..p1
  double* hmn1 = hmx1 + (size_t)B*N*C1;
  double* hmx2 = (double*)big;                                   // conv2_p0..p1
  double* hmn2 = hmx2 + (size_t)B*N*C2;
  double* base2B = hmn2 + (size_t)B*N*C2;
  float*  dist = (float*)big;                                    // dist..knn_feat
  float*  hmx3 = (float*)big;                                    // conv3_p0..p1
  float*  hmn3 = hmx3 + (size_t)B*N*C3;
  float*  baseB = hmn3 + (size_t)B*N*C3;

  float* outR1 = out + (size_t)B * N * 448;
  float* outR2 = outR1 + (size_t)B * N * 9;

  // w3 bf16 frag pack (once; independent of everything else)
  wpack_kernel<<<16, 256, 0, stream>>>(w3, wpk);

  // kNN1 — numpy-f32-faithful values, wave-parallel selection
  knn_xyz_wave<<<B*N/4, 256, 0, stream>>>(x, idx1);

  // layer 1: geometry+conv once + extremes; light BN finish
  hipMemsetAsync(sS, 0, (size_t)2*NSLICE*C3*sizeof(double), stream);
  l1_p0<<<B*N, 64, 0, stream>>>(x, nrm, w1, idx1, sS, sQ, hmx1, hmn1, outR1, outR2);
  finalize_stats<<<1, C3, 0, stream>>>(sS, sQ, mid, C1);
  l1_p1_light<<<B*N*C1/256, 256, 0, stream>>>(hmx1, hmn1, mid, g1, b1, x1d, out);

  // layer 2: base2 f64 GEMM + gather-GEMM conv (folded, r6 algebra) + light BN
  base2_kernel<<<dim3(C2/64, B*N/64), 256, 0, stream>>>(x1d, w2, base2B);
  hipMemsetAsync(sS, 0, (size_t)2*NSLICE*C3*sizeof(double), stream);
  conv2_p0<<<B*N, 128, 0, stream>>>(x1d, idx1, w2, base2B, sS, sQ, hmx2, hmn2);
  finalize_stats<<<1, C3, 0, stream>>>(sS, sQ, mid, C2);
  conv2_p1_light<<<B*N*C2/256, 256, 0, stream>>>(hmx2, hmn2, mid, g2, b2, x2d, out);

  // kNN2 — numpy-f32-faithful, all batches fused; wave-parallel coalesced top-k
  xx2f_kernel<<<B*N/64, 64, 0, stream>>>(x2d, x2f, xx2f);
  dist_f32_kernel<<<dim3(N/64, N/64, B), 256, 0, stream>>>(x2f, xx2f, dist);
  knn_feat_wave<<<B*N/4, 256, 0, stream>>>(dist, idx2);

  // layer 3: base GEMM (dist dead) + MFMA conv + extremes; light BN finish
  base_kernel<<<dim3(C3/64, B*N/64), 256, 0, stream>>>(x2f, w3, baseB);
  hipMemsetAsync(sS, 0, (size_t)2*NSLICE*C3*sizeof(double), stream);
  conv3_p0_mfma<<<B*N, 256, 0, stream>>>(x2f, idx2, wpk, baseB, sS, sQ, hmx3, hmn3);
  finalize_stats<<<1, C3, 0, stream>>>(sS, sQ, mid, C3);
  conv3_p1_light<<<B*N*C3/256, 256, 0, stream>>>(hmx3, hmn3, mid, g3, b3, out);
}